// Round 4
// baseline (1979.963 us; speedup 1.0000x reference)
//
#include <hip/hip_runtime.h>
#include <math.h>

// Problem constants
#define L_SEQ 16384
#define DM    12
#define CIN   256
#define CMID  512
#define NPOS  (L_SEQ * DM)   // 196608 spatial positions
#define DIN   24
#define DST   16

// Workspace layout (float offsets)
#define OFF_W1T   0u            // 256*512 transposed, bn1-folded W1
#define OFF_B1P   131072u       // 512 folded bias1
#define OFF_W2P   131584u       // 512 folded conv2 weight (bn2 scale folded)
#define OFF_MISC  132096u       // [0] = folded bias2
#define OFF_SEQ   132112u       // 196608 seq values
#define OFF_DELTA 328720u       // 24*16384, d-major
#define OFF_G     721936u       // 24*16384, delta*uc, d-major
#define OFF_BW    1115152u      // 16*16384, n-major
#define OFF_S     1377296u      // 24*16384 suffix sums, d-major
#define OFF_LAST  1770512u      // [0:24) uc_last, [24:40) C_last, [40:64) res_last
#define OFF_HL    1770576u      // 24*16 final h state
#define WS_FLOATS_NEEDED (OFF_HL + DIN * DST)   // 1,770,960 floats ~= 6.76 MiB

// ---------------------------------------------------------------------------
// K0: fold BN1/BN2 into weights; transpose W1 to [c][o] for uniform row reads.
// ---------------------------------------------------------------------------
__global__ void k0_prep(const float* __restrict__ W1, const float* __restrict__ b1,
                        const float* __restrict__ g1, const float* __restrict__ be1,
                        const float* __restrict__ m1, const float* __restrict__ v1,
                        const float* __restrict__ w2, const float* __restrict__ b2,
                        const float* __restrict__ g2, const float* __restrict__ be2,
                        const float* __restrict__ m2, const float* __restrict__ v2,
                        float* __restrict__ ws) {
    const int o = blockIdx.x;   // 512
    const int c = threadIdx.x;  // 256
    const float inv1 = g1[o] * rsqrtf(v1[o] + 1e-5f);
    ws[OFF_W1T + (unsigned)c * CMID + o] = W1[o * CIN + c] * inv1;
    if (c == 0) {
        ws[OFF_B1P + o] = b1[o] * inv1 + be1[o] - m1[o] * inv1;
        const float inv2 = g2[0] * rsqrtf(v2[0] + 1e-5f);
        ws[OFF_W2P + o] = w2[o] * inv2;
        if (o == 0) ws[OFF_MISC] = b2[0] * inv2 + be2[0] - m2[0] * inv2;
    }
}

// ---------------------------------------------------------------------------
// K1: fused conv1+bn1+relu+conv2+bn2+relu -> seq[196608].
// Block = 256 threads, tile = 64 positions. X tile (256c x 64p fp32 = 64KB) in
// LDS (2 blocks/CU). Each of the 4 waves owns 128 hidden channels in chunks of
// 8 (register-blocked); weight reads are wave-uniform -> scalar loads.
// ---------------------------------------------------------------------------
__launch_bounds__(256, 2)
__global__ void k1_gemm(const float* __restrict__ x, const float* __restrict__ wsr,
                        float* __restrict__ seq) {
    __shared__ float Xl[CIN * 64];  // exactly 64 KiB
    const int tid  = threadIdx.x;
    const int lane = tid & 63;
    const int wv   = __builtin_amdgcn_readfirstlane(tid >> 6);
    const long p0  = (long)blockIdx.x * 64;

    // stage X tile: 4096 float4, 16 per thread, coalesced per c-row
    #pragma unroll
    for (int it = 0; it < 16; ++it) {
        const int idx = it * 256 + tid;
        const int row = idx >> 4;
        const int c4  = (idx & 15) << 2;
        *(float4*)&Xl[row * 64 + c4] =
            *(const float4*)&x[(long)row * NPOS + p0 + c4];
    }
    __syncthreads();

    const float* __restrict__ W1T = wsr + OFF_W1T;
    const float* __restrict__ b1p = wsr + OFF_B1P;
    const float* __restrict__ w2p = wsr + OFF_W2P;

    float sp = 0.f;  // this lane's partial conv2 sum for position p0+lane
    for (int ch = 0; ch < 16; ++ch) {
        const int o0 = ch * 32 + wv * 8;          // wave-uniform
        float acc[8];
        #pragma unroll
        for (int j = 0; j < 8; ++j) acc[j] = 0.f;
        const float* wb = W1T + o0;
        #pragma unroll 4
        for (int c = 0; c < CIN; ++c) {
            const float xv = Xl[c * 64 + lane];
            const float* wr = wb + c * CMID;      // uniform address
            #pragma unroll
            for (int j = 0; j < 8; ++j) acc[j] = fmaf(wr[j], xv, acc[j]);
        }
        #pragma unroll
        for (int j = 0; j < 8; ++j) {
            float h = acc[j] + b1p[o0 + j];
            h = fmaxf(h, 0.f);
            sp = fmaf(w2p[o0 + j], h, sp);
        }
    }

    // cross-wave reduce (reuse LDS)
    __syncthreads();
    Xl[wv * 64 + lane] = sp;
    __syncthreads();
    if (wv == 0) {
        const float b2p = wsr[OFF_MISC];
        const float s = Xl[lane] + Xl[64 + lane] + Xl[128 + lane] + Xl[192 + lane];
        seq[p0 + lane] = fmaxf(s + b2p, 0.f);
    }
}

// ---------------------------------------------------------------------------
// K2: per-position Mamba front-end: in_proj -> causal depthwise conv1d ->
// silu -> x_proj -> delta(softplus). Emits delta, g=delta*uc, B, and the
// last-position extras (uc_last, C_last, res_last). One thread per l.
// ---------------------------------------------------------------------------
__global__ void k2_front(const float* __restrict__ seq, const float* __restrict__ ipw,
                         const float* __restrict__ cw,  const float* __restrict__ cb,
                         const float* __restrict__ xp,  const float* __restrict__ dtw,
                         const float* __restrict__ dtb, float* __restrict__ ws) {
    const int l = blockIdx.x * 256 + threadIdx.x;  // 0..16383

    // seq rows l-3..l (12 floats each)
    float srow[4][12];
    #pragma unroll
    for (int k = 0; k < 4; ++k) {
        const int t = l - 3 + k;
        if (t >= 0) {
            #pragma unroll
            for (int q = 0; q < 3; ++q) {
                const float4 v = *(const float4*)&seq[t * 12 + q * 4];
                srow[k][q * 4 + 0] = v.x; srow[k][q * 4 + 1] = v.y;
                srow[k][q * 4 + 2] = v.z; srow[k][q * 4 + 3] = v.w;
            }
        } else {
            #pragma unroll
            for (int m = 0; m < 12; ++m) srow[k][m] = 0.f;
        }
    }

    // uc[d] = silu(conv1d_b[d] + sum_k cw[d,k] * u[l-3+k, d])
    float uc[DIN];
    #pragma unroll
    for (int d = 0; d < DIN; ++d) {
        float a = cb[d];
        #pragma unroll
        for (int k = 0; k < 4; ++k) {
            float uv = 0.f;
            #pragma unroll
            for (int m = 0; m < 12; ++m) uv = fmaf(srow[k][m], ipw[d * 12 + m], uv);
            a = fmaf(cw[d * 4 + k], uv, a);
        }
        uc[d] = a / (1.f + __expf(-a));  // silu
    }

    // dt-rank part of x_dbl
    float dtr[4];
    #pragma unroll
    for (int r = 0; r < 4; ++r) {
        float s = 0.f;
        #pragma unroll
        for (int d = 0; d < DIN; ++d) s = fmaf(uc[d], xp[r * DIN + d], s);
        dtr[r] = s;
    }

    // delta + g
    #pragma unroll
    for (int d = 0; d < DIN; ++d) {
        float dp = dtb[d];
        #pragma unroll
        for (int r = 0; r < 4; ++r) dp = fmaf(dtw[d * 4 + r], dtr[r], dp);
        const float de = (dp > 20.f) ? dp : log1pf(__expf(dp));
        ws[OFF_DELTA + (unsigned)d * L_SEQ + l] = de;
        ws[OFF_G     + (unsigned)d * L_SEQ + l] = de * uc[d];
    }

    // B
    #pragma unroll
    for (int n = 0; n < DST; ++n) {
        float bv = 0.f;
        #pragma unroll
        for (int d = 0; d < DIN; ++d) bv = fmaf(uc[d], xp[(4 + n) * DIN + d], bv);
        ws[OFF_BW + (unsigned)n * L_SEQ + l] = bv;
    }

    // last-position extras
    if (l == L_SEQ - 1) {
        #pragma unroll
        for (int d = 0; d < DIN; ++d) ws[OFF_LAST + d] = uc[d];
        #pragma unroll
        for (int n = 0; n < DST; ++n) {
            float cv = 0.f;
            #pragma unroll
            for (int d = 0; d < DIN; ++d) cv = fmaf(uc[d], xp[(20 + n) * DIN + d], cv);
            ws[OFF_LAST + 24 + n] = cv;
        }
        #pragma unroll
        for (int d = 0; d < DIN; ++d) {
            float rv = 0.f;
            #pragma unroll
            for (int m = 0; m < 12; ++m) rv = fmaf(srow[3][m], ipw[(DIN + d) * 12 + m], rv);
            ws[OFF_LAST + 40 + d] = rv;
        }
    }
}

// ---------------------------------------------------------------------------
// K3: per-channel suffix sums S_t[d] = sum_{s>t} delta[s,d]  (fp64 accumulate)
// One block per channel d; 256 threads x 64-element chunks.
// ---------------------------------------------------------------------------
__global__ void k3_scan(const float* __restrict__ delta, float* __restrict__ S) {
    const int d = blockIdx.x;
    const float* dp_ = delta + (size_t)d * L_SEQ;
    float* Sp = S + (size_t)d * L_SEQ;
    const int tid = threadIdx.x;
    __shared__ double part[256];

    double cs = 0.0;
    const int base = tid * 64;
    for (int i = 0; i < 64; ++i) cs += (double)dp_[base + i];
    part[tid] = cs;
    __syncthreads();
    if (tid == 0) {
        double r = 0.0;
        for (int i = 0; i < 256; ++i) { r += part[i]; part[i] = r; }
    }
    __syncthreads();
    const double total = part[255];
    double run = (tid == 0) ? 0.0 : part[tid - 1];
    for (int i = 0; i < 64; ++i) {
        run += (double)dp_[base + i];
        Sp[base + i] = (float)(total - run);  // suffix sum excluding t
    }
}

// ---------------------------------------------------------------------------
// K4: h_L[d,n] = sum_t exp(A[d,n]*S_t[d]) * g[t,d] * B[t,n]
// One block per channel d; block-reduce the 16 n-accumulators.
// ---------------------------------------------------------------------------
__launch_bounds__(256)
__global__ void k4_reduce(const float* __restrict__ A_log, const float* __restrict__ wsr,
                          float* __restrict__ hL) {
    const int d = blockIdx.x;
    const int tid = threadIdx.x;
    float Ar[DST];
    #pragma unroll
    for (int n = 0; n < DST; ++n) Ar[n] = -__expf(A_log[d * DST + n]);

    const float* Sp = wsr + OFF_S + (size_t)d * L_SEQ;
    const float* Gp = wsr + OFF_G + (size_t)d * L_SEQ;
    const float* Bp = wsr + OFF_BW;

    float acc[DST];
    #pragma unroll
    for (int n = 0; n < DST; ++n) acc[n] = 0.f;

    for (int t = tid; t < L_SEQ; t += 256) {
        const float s  = Sp[t];
        const float gv = Gp[t];
        #pragma unroll
        for (int n = 0; n < DST; ++n) {
            const float w = __expf(Ar[n] * s) * gv;
            acc[n] = fmaf(w, Bp[n * L_SEQ + t], acc[n]);
        }
    }

    __shared__ float red[256 * DST];
    #pragma unroll
    for (int n = 0; n < DST; ++n) red[n * 256 + tid] = acc[n];
    __syncthreads();
    for (int st = 128; st >= 1; st >>= 1) {
        if (tid < st) {
            #pragma unroll
            for (int n = 0; n < DST; ++n) red[n * 256 + tid] += red[n * 256 + tid + st];
        }
        __syncthreads();
    }
    if (tid < DST) hL[d * DST + tid] = red[tid * 256];
}

// ---------------------------------------------------------------------------
// K5: finalize -> single scalar output.
// ---------------------------------------------------------------------------
__global__ void k5_final(const float* __restrict__ wsr, const float* __restrict__ Dp,
                         const float* __restrict__ opw, const float* __restrict__ linw,
                         const float* __restrict__ linb, float* __restrict__ out) {
    __shared__ float ybuf[DIN];
    __shared__ float obuf[DM];
    const int tid = threadIdx.x;  // 64
    const float* hL   = wsr + OFF_HL;
    const float* last = wsr + OFF_LAST;

    if (tid < DIN) {
        float y = 0.f;
        #pragma unroll
        for (int n = 0; n < DST; ++n) y = fmaf(hL[tid * DST + n], last[24 + n], y);
        y = fmaf(last[tid], Dp[tid], y);          // + uc_last * D
        const float r = last[40 + tid];           // res_last
        y *= r / (1.f + __expf(-r));              // * silu(res)
        ybuf[tid] = y;
    }
    __syncthreads();
    if (tid < DM) {
        float o = 0.f;
        #pragma unroll
        for (int dd = 0; dd < DIN; ++dd) o = fmaf(ybuf[dd], opw[tid * DIN + dd], o);
        obuf[tid] = o;
    }
    __syncthreads();
    if (tid == 0) {
        float p = linb[0];
        #pragma unroll
        for (int e = 0; e < DM; ++e) p = fmaf(obuf[e], linw[e], p);
        out[0] = p;
    }
}

// ---------------------------------------------------------------------------
// Sentinel: launched instead of the pipeline if ws_size is too small, so we
// never write OOB into d_ws (a container-killer). out = -12345 marks this
// path unambiguously in the validation report.
// ---------------------------------------------------------------------------
__global__ void k_ws_too_small(float* __restrict__ out) {
    if (threadIdx.x == 0 && blockIdx.x == 0) out[0] = -12345.0f;
}

// ---------------------------------------------------------------------------
extern "C" void kernel_launch(void* const* d_in, const int* in_sizes, int n_in,
                              void* d_out, int out_size, void* d_ws, size_t ws_size,
                              hipStream_t stream) {
    (void)in_sizes; (void)n_in; (void)out_size;
    float* out = (float*)d_out;
    if (ws_size < (size_t)WS_FLOATS_NEEDED * sizeof(float)) {
        k_ws_too_small<<<dim3(1), dim3(64), 0, stream>>>(out);
        return;
    }

    const float* x    = (const float*)d_in[0];
    const float* w1   = (const float*)d_in[1];
    const float* b1   = (const float*)d_in[2];
    const float* g1   = (const float*)d_in[3];
    const float* be1  = (const float*)d_in[4];
    const float* m1   = (const float*)d_in[5];
    const float* v1   = (const float*)d_in[6];
    const float* w2   = (const float*)d_in[7];
    const float* b2   = (const float*)d_in[8];
    const float* g2   = (const float*)d_in[9];
    const float* be2  = (const float*)d_in[10];
    const float* m2   = (const float*)d_in[11];
    const float* v2   = (const float*)d_in[12];
    const float* ipw  = (const float*)d_in[13];  // in_proj_w (48,12)
    const float* cw   = (const float*)d_in[14];  // conv1d_w (24,1,4)
    const float* cb   = (const float*)d_in[15];  // conv1d_b (24)
    const float* xp   = (const float*)d_in[16];  // x_proj_w (36,24)
    const float* dtw  = (const float*)d_in[17];  // dt_proj_w (24,4)
    const float* dtb  = (const float*)d_in[18];  // dt_proj_b (24)
    const float* alog = (const float*)d_in[19];  // A_log (24,16)
    const float* Dp   = (const float*)d_in[20];  // D (24)
    const float* opw  = (const float*)d_in[21];  // out_proj_w (12,24)
    const float* linw = (const float*)d_in[22];  // lin_w (1,12)
    const float* linb = (const float*)d_in[23];  // lin_b (1)

    float* ws = (float*)d_ws;

    k0_prep<<<dim3(CMID), dim3(CIN), 0, stream>>>(w1, b1, g1, be1, m1, v1,
                                                  w2, b2, g2, be2, m2, v2, ws);
    k1_gemm<<<dim3(NPOS / 64), dim3(256), 0, stream>>>(x, ws, ws + OFF_SEQ);
    k2_front<<<dim3(L_SEQ / 256), dim3(256), 0, stream>>>(ws + OFF_SEQ, ipw, cw, cb,
                                                          xp, dtw, dtb, ws);
    k3_scan<<<dim3(DIN), dim3(256), 0, stream>>>(ws + OFF_DELTA, ws + OFF_S);
    k4_reduce<<<dim3(DIN), dim3(256), 0, stream>>>(alog, ws, ws + OFF_HL);
    k5_final<<<dim3(1), dim3(64), 0, stream>>>(ws, Dp, opw, linw, linb, out);
}

// Round 6
// 1595.332 us; speedup vs baseline: 1.2411x; 1.2411x over previous
//
#include <hip/hip_runtime.h>
#include <math.h>

// Problem constants
#define L_SEQ 16384
#define DM    12
#define CIN   256
#define CMID  512
#define NPOS  (L_SEQ * DM)   // 196608 spatial positions
#define DIN   24
#define DST   16

// Workspace layout (float offsets)
#define OFF_W1T   0u            // 256*512 transposed, bn1-folded W1
#define OFF_B1P   131072u       // 512 folded bias1
#define OFF_W2P   131584u       // 512 folded conv2 weight (bn2 scale folded)
#define OFF_MISC  132096u       // [0] = folded bias2
#define OFF_SEQ   132112u       // 196608 seq values
#define OFF_DELTA 328720u       // 24*16384, d-major
#define OFF_G     721936u       // 24*16384, delta*uc, d-major
#define OFF_BW    1115152u      // 16*16384, n-major
#define OFF_S     1377296u      // 24*16384 suffix sums, d-major
#define OFF_LAST  1770512u      // [0:24) uc_last, [24:40) C_last, [40:64) res_last
#define OFF_HL    1770576u      // 24*8*16 k4 partials (k5 sums them)
#define WS_FLOATS_NEEDED (OFF_HL + DIN * 8 * DST)   // 1,773,648 floats ~= 6.77 MiB

// ---------------------------------------------------------------------------
// K0: fold BN1/BN2 into weights; transpose W1 to [c][o].
// block = c (256), thread = o (512) -> ws writes coalesced.
// ---------------------------------------------------------------------------
__global__ void k0_prep(const float* __restrict__ W1, const float* __restrict__ b1,
                        const float* __restrict__ g1, const float* __restrict__ be1,
                        const float* __restrict__ m1, const float* __restrict__ v1,
                        const float* __restrict__ w2, const float* __restrict__ b2,
                        const float* __restrict__ g2, const float* __restrict__ be2,
                        const float* __restrict__ m2, const float* __restrict__ v2,
                        float* __restrict__ ws) {
    const int c = blockIdx.x;   // 256
    const int o = threadIdx.x;  // 512
    const float inv1 = g1[o] * rsqrtf(v1[o] + 1e-5f);
    ws[OFF_W1T + (unsigned)c * CMID + o] = W1[o * CIN + c] * inv1;
    if (c == 0) {
        ws[OFF_B1P + o] = b1[o] * inv1 + be1[o] - m1[o] * inv1;
        const float inv2 = g2[0] * rsqrtf(v2[0] + 1e-5f);
        ws[OFF_W2P + o] = w2[o] * inv2;
        if (o == 0) ws[OFF_MISC] = b2[0] * inv2 + be2[0] - m2[0] * inv2;
    }
}

// ---------------------------------------------------------------------------
// K1 v2: fused conv1+bn1+relu+conv2+bn2+relu -> seq[196608].
// Measured v1: VALUBusy 24.9% -> issue-bound (1 ds_read_b32 + 2 vmem per
// 8 FMA). v2: o-block 16 per lane (16 FMA per x-value), c-pairs so the two
// x-reads merge into one ds_read2_b32, weight addresses wave-uniform
// (readfirstlane) to scalarize into s_load; unroll 4 batches loads.
// ---------------------------------------------------------------------------
__launch_bounds__(256, 2)
__global__ void k1_gemm(const float* __restrict__ x, const float* __restrict__ wsr,
                        float* __restrict__ seq) {
    __shared__ float Xl[CIN * 64];  // 64 KiB, [c][p]
    const int tid  = threadIdx.x;
    const int lane = tid & 63;
    const int wv   = __builtin_amdgcn_readfirstlane(tid >> 6);
    const long p0  = (long)blockIdx.x * 64;

    // stage X tile: 4096 float4, 16 per thread, coalesced per c-row
    #pragma unroll
    for (int it = 0; it < 16; ++it) {
        const int idx = it * 256 + tid;
        const int row = idx >> 4;
        const int c4  = (idx & 15) << 2;
        *(float4*)&Xl[row * 64 + c4] =
            *(const float4*)&x[(long)row * NPOS + p0 + c4];
    }
    __syncthreads();

    const float* __restrict__ W1T = wsr + OFF_W1T;
    const float* __restrict__ b1p = wsr + OFF_B1P;
    const float* __restrict__ w2p = wsr + OFF_W2P;

    float sp = 0.f;  // this lane's partial conv2 sum for position p0+lane
    #pragma unroll 1
    for (int ch = 0; ch < 8; ++ch) {
        const int o0 = __builtin_amdgcn_readfirstlane(wv * 128 + ch * 16);
        float acc[16];
        #pragma unroll
        for (int j = 0; j < 16; ++j) acc[j] = 0.f;

        #pragma unroll 4
        for (int c = 0; c < CIN; c += 2) {
            // two x-values; adjacent ds_read_b32 offsets (64 dwords apart)
            // merge into one ds_read2_b32
            const float xv0 = Xl[c * 64 + lane];
            const float xv1 = Xl[(c + 1) * 64 + lane];
            // wave-uniform weight rows -> scalar loads
            const float4* wq0 = (const float4*)(W1T + (size_t)c * CMID + o0);
            const float4* wq1 = (const float4*)(W1T + (size_t)(c + 1) * CMID + o0);
            float w0[16], w1[16];
            *(float4*)&w0[0]  = wq0[0]; *(float4*)&w0[4]  = wq0[1];
            *(float4*)&w0[8]  = wq0[2]; *(float4*)&w0[12] = wq0[3];
            *(float4*)&w1[0]  = wq1[0]; *(float4*)&w1[4]  = wq1[1];
            *(float4*)&w1[8]  = wq1[2]; *(float4*)&w1[12] = wq1[3];
            #pragma unroll
            for (int j = 0; j < 16; ++j) acc[j] = fmaf(w0[j], xv0, acc[j]);
            #pragma unroll
            for (int j = 0; j < 16; ++j) acc[j] = fmaf(w1[j], xv1, acc[j]);
        }

        #pragma unroll
        for (int j = 0; j < 16; ++j) {
            float h = acc[j] + b1p[o0 + j];
            h = fmaxf(h, 0.f);
            sp = fmaf(w2p[o0 + j], h, sp);
        }
    }

    // cross-wave reduce (reuse LDS)
    __syncthreads();
    Xl[wv * 64 + lane] = sp;
    __syncthreads();
    if (wv == 0) {
        const float b2p = wsr[OFF_MISC];
        const float s = Xl[lane] + Xl[64 + lane] + Xl[128 + lane] + Xl[192 + lane];
        seq[p0 + lane] = fmaxf(s + b2p, 0.f);
    }
}

// ---------------------------------------------------------------------------
// K2: per-position Mamba front-end (unchanged math; grid 128x128 for spread).
// ---------------------------------------------------------------------------
__global__ void k2_front(const float* __restrict__ seq, const float* __restrict__ ipw,
                         const float* __restrict__ cw,  const float* __restrict__ cb,
                         const float* __restrict__ xp,  const float* __restrict__ dtw,
                         const float* __restrict__ dtb, float* __restrict__ ws) {
    const int l = blockIdx.x * 128 + threadIdx.x;  // 0..16383

    float srow[4][12];
    #pragma unroll
    for (int k = 0; k < 4; ++k) {
        const int t = l - 3 + k;
        if (t >= 0) {
            #pragma unroll
            for (int q = 0; q < 3; ++q) {
                const float4 v = *(const float4*)&seq[t * 12 + q * 4];
                srow[k][q * 4 + 0] = v.x; srow[k][q * 4 + 1] = v.y;
                srow[k][q * 4 + 2] = v.z; srow[k][q * 4 + 3] = v.w;
            }
        } else {
            #pragma unroll
            for (int m = 0; m < 12; ++m) srow[k][m] = 0.f;
        }
    }

    float uc[DIN];
    #pragma unroll
    for (int d = 0; d < DIN; ++d) {
        float a = cb[d];
        #pragma unroll
        for (int k = 0; k < 4; ++k) {
            float uv = 0.f;
            #pragma unroll
            for (int m = 0; m < 12; ++m) uv = fmaf(srow[k][m], ipw[d * 12 + m], uv);
            a = fmaf(cw[d * 4 + k], uv, a);
        }
        uc[d] = a / (1.f + __expf(-a));  // silu
    }

    float dtr[4];
    #pragma unroll
    for (int r = 0; r < 4; ++r) {
        float s = 0.f;
        #pragma unroll
        for (int d = 0; d < DIN; ++d) s = fmaf(uc[d], xp[r * DIN + d], s);
        dtr[r] = s;
    }

    #pragma unroll
    for (int d = 0; d < DIN; ++d) {
        float dp = dtb[d];
        #pragma unroll
        for (int r = 0; r < 4; ++r) dp = fmaf(dtw[d * 4 + r], dtr[r], dp);
        const float de = (dp > 20.f) ? dp : log1pf(__expf(dp));
        ws[OFF_DELTA + (unsigned)d * L_SEQ + l] = de;
        ws[OFF_G     + (unsigned)d * L_SEQ + l] = de * uc[d];
    }

    #pragma unroll
    for (int n = 0; n < DST; ++n) {
        float bv = 0.f;
        #pragma unroll
        for (int d = 0; d < DIN; ++d) bv = fmaf(uc[d], xp[(4 + n) * DIN + d], bv);
        ws[OFF_BW + (unsigned)n * L_SEQ + l] = bv;
    }

    if (l == L_SEQ - 1) {
        #pragma unroll
        for (int d = 0; d < DIN; ++d) ws[OFF_LAST + d] = uc[d];
        #pragma unroll
        for (int n = 0; n < DST; ++n) {
            float cv = 0.f;
            #pragma unroll
            for (int d = 0; d < DIN; ++d) cv = fmaf(uc[d], xp[(20 + n) * DIN + d], cv);
            ws[OFF_LAST + 24 + n] = cv;
        }
        #pragma unroll
        for (int d = 0; d < DIN; ++d) {
            float rv = 0.f;
            #pragma unroll
            for (int m = 0; m < 12; ++m) rv = fmaf(srow[3][m], ipw[(DIN + d) * 12 + m], rv);
            ws[OFF_LAST + 40 + d] = rv;
        }
    }
}

// ---------------------------------------------------------------------------
// K3: per-channel suffix sums S_t[d] = sum_{s>t} delta[s,d]  (fp64 accumulate)
// ---------------------------------------------------------------------------
__global__ void k3_scan(const float* __restrict__ delta, float* __restrict__ S) {
    const int d = blockIdx.x;
    const float* dp_ = delta + (size_t)d * L_SEQ;
    float* Sp = S + (size_t)d * L_SEQ;
    const int tid = threadIdx.x;
    __shared__ double part[256];

    double cs = 0.0;
    const int base = tid * 64;
    for (int i = 0; i < 64; ++i) cs += (double)dp_[base + i];
    part[tid] = cs;
    __syncthreads();
    if (tid == 0) {
        double r = 0.0;
        for (int i = 0; i < 256; ++i) { r += part[i]; part[i] = r; }
    }
    __syncthreads();
    const double total = part[255];
    double run = (tid == 0) ? 0.0 : part[tid - 1];
    for (int i = 0; i < 64; ++i) {
        run += (double)dp_[base + i];
        Sp[base + i] = (float)(total - run);  // suffix sum excluding t
    }
}

// ---------------------------------------------------------------------------
// K4: partial h_L over t-chunks: part[d][chunk][n] = sum_{t in chunk}
// exp(A[d,n]*S_t[d]) * g[t,d] * B[t,n].  Grid 24*8 (was 24 -> 8x parallelism).
// k5 sums the 8 partials deterministically.
// ---------------------------------------------------------------------------
__launch_bounds__(256)
__global__ void k4_reduce(const float* __restrict__ A_log, const float* __restrict__ wsr,
                          float* __restrict__ part) {
    const int d     = blockIdx.x >> 3;   // 0..23
    const int chunk = blockIdx.x & 7;    // 0..7
    const int tid   = threadIdx.x;
    float Ar[DST];
    #pragma unroll
    for (int n = 0; n < DST; ++n) Ar[n] = -__expf(A_log[d * DST + n]);

    const float* Sp = wsr + OFF_S + (size_t)d * L_SEQ;
    const float* Gp = wsr + OFF_G + (size_t)d * L_SEQ;
    const float* Bp = wsr + OFF_BW;

    float acc[DST];
    #pragma unroll
    for (int n = 0; n < DST; ++n) acc[n] = 0.f;

    const int t0 = chunk * (L_SEQ / 8);
    const int t1 = t0 + (L_SEQ / 8);
    for (int t = t0 + tid; t < t1; t += 256) {
        const float s  = Sp[t];
        const float gv = Gp[t];
        #pragma unroll
        for (int n = 0; n < DST; ++n) {
            const float w = __expf(Ar[n] * s) * gv;
            acc[n] = fmaf(w, Bp[n * L_SEQ + t], acc[n]);
        }
    }

    __shared__ float red[256 * DST];
    #pragma unroll
    for (int n = 0; n < DST; ++n) red[n * 256 + tid] = acc[n];
    __syncthreads();
    for (int st = 128; st >= 1; st >>= 1) {
        if (tid < st) {
            #pragma unroll
            for (int n = 0; n < DST; ++n) red[n * 256 + tid] += red[n * 256 + tid + st];
        }
        __syncthreads();
    }
    if (tid < DST) part[(size_t)blockIdx.x * DST + tid] = red[tid * 256];
}

// ---------------------------------------------------------------------------
// K5: finalize -> single scalar output (sums k4's 8 partials per (d,n)).
// ---------------------------------------------------------------------------
__global__ void k5_final(const float* __restrict__ wsr, const float* __restrict__ Dp,
                         const float* __restrict__ opw, const float* __restrict__ linw,
                         const float* __restrict__ linb, float* __restrict__ out) {
    __shared__ float ybuf[DIN];
    __shared__ float obuf[DM];
    const int tid = threadIdx.x;  // 64
    const float* part = wsr + OFF_HL;
    const float* last = wsr + OFF_LAST;

    if (tid < DIN) {
        float y = 0.f;
        #pragma unroll
        for (int n = 0; n < DST; ++n) {
            float h = 0.f;
            #pragma unroll
            for (int k = 0; k < 8; ++k) h += part[(size_t)(tid * 8 + k) * DST + n];
            y = fmaf(h, last[24 + n], y);
        }
        y = fmaf(last[tid], Dp[tid], y);          // + uc_last * D
        const float r = last[40 + tid];           // res_last
        y *= r / (1.f + __expf(-r));              // * silu(res)
        ybuf[tid] = y;
    }
    __syncthreads();
    if (tid < DM) {
        float o = 0.f;
        #pragma unroll
        for (int dd = 0; dd < DIN; ++dd) o = fmaf(ybuf[dd], opw[tid * DIN + dd], o);
        obuf[tid] = o;
    }
    __syncthreads();
    if (tid == 0) {
        float p = linb[0];
        #pragma unroll
        for (int e = 0; e < DM; ++e) p = fmaf(obuf[e], linw[e], p);
        out[0] = p;
    }
}

// ---------------------------------------------------------------------------
__global__ void k_ws_too_small(float* __restrict__ out) {
    if (threadIdx.x == 0 && blockIdx.x == 0) out[0] = -12345.0f;
}

// ---------------------------------------------------------------------------
extern "C" void kernel_launch(void* const* d_in, const int* in_sizes, int n_in,
                              void* d_out, int out_size, void* d_ws, size_t ws_size,
                              hipStream_t stream) {
    (void)in_sizes; (void)n_in; (void)out_size;
    float* out = (float*)d_out;
    if (ws_size < (size_t)WS_FLOATS_NEEDED * sizeof(float)) {
        k_ws_too_small<<<dim3(1), dim3(64), 0, stream>>>(out);
        return;
    }

    const float* x    = (const float*)d_in[0];
    const float* w1   = (const float*)d_in[1];
    const float* b1   = (const float*)d_in[2];
    const float* g1   = (const float*)d_in[3];
    const float* be1  = (const float*)d_in[4];
    const float* m1   = (const float*)d_in[5];
    const float* v1   = (const float*)d_in[6];
    const float* w2   = (const float*)d_in[7];
    const float* b2   = (const float*)d_in[8];
    const float* g2   = (const float*)d_in[9];
    const float* be2  = (const float*)d_in[10];
    const float* m2   = (const float*)d_in[11];
    const float* v2   = (const float*)d_in[12];
    const float* ipw  = (const float*)d_in[13];  // in_proj_w (48,12)
    const float* cw   = (const float*)d_in[14];  // conv1d_w (24,1,4)
    const float* cb   = (const float*)d_in[15];  // conv1d_b (24)
    const float* xp   = (const float*)d_in[16];  // x_proj_w (36,24)
    const float* dtw  = (const float*)d_in[17];  // dt_proj_w (24,4)
    const float* dtb  = (const float*)d_in[18];  // dt_proj_b (24)
    const float* alog = (const float*)d_in[19];  // A_log (24,16)
    const float* Dp   = (const float*)d_in[20];  // D (24)
    const float* opw  = (const float*)d_in[21];  // out_proj_w (12,24)
    const float* linw = (const float*)d_in[22];  // lin_w (1,12)
    const float* linb = (const float*)d_in[23];  // lin_b (1)

    float* ws = (float*)d_ws;

    k0_prep<<<dim3(CIN), dim3(CMID), 0, stream>>>(w1, b1, g1, be1, m1, v1,
                                                  w2, b2, g2, be2, m2, v2, ws);
    k1_gemm<<<dim3(NPOS / 64), dim3(256), 0, stream>>>(x, ws, ws + OFF_SEQ);
    k2_front<<<dim3(L_SEQ / 128), dim3(128), 0, stream>>>(ws + OFF_SEQ, ipw, cw, cb,
                                                          xp, dtw, dtb, ws);
    k3_scan<<<dim3(DIN), dim3(256), 0, stream>>>(ws + OFF_DELTA, ws + OFF_S);
    k4_reduce<<<dim3(DIN * 8), dim3(256), 0, stream>>>(alog, ws, ws + OFF_HL);
    k5_final<<<dim3(1), dim3(64), 0, stream>>>(ws, Dp, opw, linw, linb, out);
}